// Round 6
// baseline (159.344 us; speedup 1.0000x reference)
//
#include <hip/hip_runtime.h>
#include <hip/hip_bf16.h>

#define NROW 8192   // B*A = 64*128
#define INC  128
#define OUTC 64

typedef __bf16 bf16x8 __attribute__((ext_vector_type(8)));
typedef __bf16 bf16x2 __attribute__((ext_vector_type(2)));
typedef float  f32x4  __attribute__((ext_vector_type(4)));

static __device__ __forceinline__ f32x4 mfma16(bf16x8 a, bf16x8 b, f32x4 c) {
    return __builtin_amdgcn_mfma_f32_16x16x32_bf16(a, b, c, 0, 0, 0);
}

static __device__ __forceinline__ bf16x8 cvt8(float4 lo, float4 hi) {
    bf16x8 r;
    r[0] = (__bf16)lo.x; r[1] = (__bf16)lo.y; r[2] = (__bf16)lo.z; r[3] = (__bf16)lo.w;
    r[4] = (__bf16)hi.x; r[5] = (__bf16)hi.y; r[6] = (__bf16)hi.z; r[7] = (__bf16)hi.w;
    return r;
}

static __device__ __forceinline__ int pack_bf2(float a, float b) {
    bf16x2 t; t[0] = (__bf16)a; t[1] = (__bf16)b;
    union { bf16x2 v; int i; } u; u.v = t;
    return u.i;
}

// ---------------------------------------------------------------------------
// Kernel 1: projection via MFMA. grid = 768 = mat(3) x b(64) x aq(4).
// mat 0 -> q, 1 -> k (row-major bf16), 2 -> vT (transposed) + normalized vnb.
__global__ __launch_bounds__(256) void proj_kernel(
    const float* __restrict__ feat,
    const float* __restrict__ Wq, const float* __restrict__ bq,
    const float* __restrict__ Wk, const float* __restrict__ bk,
    const float* __restrict__ Wv, const float* __restrict__ bv,
    __hip_bfloat16* __restrict__ qb, __hip_bfloat16* __restrict__ kb,
    __hip_bfloat16* __restrict__ vT, __hip_bfloat16* __restrict__ vnb)
{
    __shared__ float slab[32 * 132];   // f[a][c], pad-132
    __shared__ float vbuf[32 * 66];    // V staging [r][c], pad-66
    __shared__ float invb[32];

    const int blk = blockIdx.x;
    const int mat = blk >> 8;                 // 0,1,2
    const int b   = (blk >> 2) & 63;
    const int a0  = (blk & 3) * 32;
    const int r0  = b * 128 + a0;
    const float* fb = feat + (size_t)b * INC * 128;

    for (int i = threadIdx.x; i < 32 * 128; i += 256) {
        int c = i >> 5, a = i & 31;
        slab[a * 132 + c] = fb[c * 128 + a0 + a];
    }
    __syncthreads();

    const int w    = threadIdx.x >> 6;
    const int lane = threadIdx.x & 63;
    const int l16  = lane & 15;
    const int quad = lane >> 4;
    const int n0   = w * 16;

    const float* W    = (mat == 0) ? Wq : (mat == 1) ? Wk : Wv;
    const float* bias = (mat == 0) ? bq : (mat == 1) ? bk : bv;

    f32x4 acc[2] = {{0.f,0.f,0.f,0.f},{0.f,0.f,0.f,0.f}};
    #pragma unroll
    for (int kc = 0; kc < 4; ++kc) {
        const int k0 = kc * 32 + quad * 8;
        const float* wr = W + (n0 + l16) * INC + k0;
        bf16x8 bfr = cvt8(*(const float4*)wr, *(const float4*)(wr + 4));
        #pragma unroll
        for (int u = 0; u < 2; ++u) {
            const float* ar = slab + (u * 16 + l16) * 132 + k0;
            bf16x8 afr = cvt8(*(const float4*)ar, *(const float4*)(ar + 4));
            acc[u] = mfma16(afr, bfr, acc[u]);
        }
    }
    const float bl = bias[n0 + l16];

    if (mat < 2) {
        __hip_bfloat16* dst = mat ? kb : qb;
        #pragma unroll
        for (int u = 0; u < 2; ++u)
            #pragma unroll
            for (int r = 0; r < 4; ++r)
                dst[(r0 + u * 16 + quad * 4 + r) * OUTC + n0 + l16] =
                    __float2bfloat16(acc[u][r] + bl);
    } else {
        #pragma unroll
        for (int u = 0; u < 2; ++u)
            #pragma unroll
            for (int r = 0; r < 4; ++r)
                vbuf[(u * 16 + quad * 4 + r) * 66 + n0 + l16] = acc[u][r] + bl;
        __syncthreads();
        // coalesced transposed store for attention's vT
        const int c  = threadIdx.x >> 2;
        const int rc = threadIdx.x & 3;
        bf16x8 pack;
        #pragma unroll
        for (int i = 0; i < 8; ++i)
            pack[i] = (__bf16)vbuf[(rc * 8 + i) * 66 + c];
        *(bf16x8*)(vT + (size_t)c * NROW + r0 + rc * 8) = pack;
        // row norms: thread (rl = tid>>3, jj = tid&7)
        const int rl = threadIdx.x >> 3;
        const int jj = threadIdx.x & 7;
        float ss = 0.f;
        #pragma unroll
        for (int i = 0; i < 8; ++i) {
            float x = vbuf[rl * 66 + jj * 8 + i];
            ss += x * x;
        }
        ss += __shfl_xor(ss, 1, 64);
        ss += __shfl_xor(ss, 2, 64);
        ss += __shfl_xor(ss, 4, 64);
        if (jj == 0) invb[rl] = rsqrtf(fmaxf(ss, 1e-24f));
        __syncthreads();   // cross-lane LDS write -> read ordering
        float inv = invb[rl];
        bf16x8 vp;
        #pragma unroll
        for (int i = 0; i < 8; ++i)
            vp[i] = (__bf16)(vbuf[rl * 66 + jj * 8 + i] * inv);
        *(bf16x8*)(vnb + (size_t)(r0 + rl) * 64 + jj * 8) = vp;
    }
}

// ---------------------------------------------------------------------------
// Kernel 2: no-max exp-sum attention, split-K G=16, barrier-free.
// S^T = K·Q^T orientation (swapped MFMA operands). C-layout->A-layout P
// transpose via ds_bpermute (fixed pattern: dest quad q pulls src quads
// {(q&1)*2, +1}, tile h=q>>1, same l16). Partials atomicAdd'ed into
// L2-resident Oacc (2 MB) / lacc (32 KB). No LDS, no __syncthreads.
__global__ __launch_bounds__(64, 4) void attn_kernel(
    const __hip_bfloat16* __restrict__ qb,
    const __hip_bfloat16* __restrict__ kb,
    const __hip_bfloat16* __restrict__ vT,
    float* __restrict__ Oacc, float* __restrict__ lacc)
{
    const int task = blockIdx.x;
    const int tile = task & 255;
    const int g    = task >> 8;
    const int r0   = tile * 32;
    const int lane = threadIdx.x;
    const int l16  = lane & 15;
    const int quad = lane >> 4;
    const int kpg  = NROW / 16;
    const int iters = kpg >> 5;      // 16

    bf16x8 qf[2][2];
    #pragma unroll
    for (int u = 0; u < 2; ++u)
        #pragma unroll
        for (int kc = 0; kc < 2; ++kc)
            qf[u][kc] = *(const bf16x8*)(qb + (r0 + u * 16 + l16) * 64 + kc * 32 + quad * 8);

    f32x4 of[2][4];
    float lp[2] = {0.f, 0.f};
    #pragma unroll
    for (int u = 0; u < 2; ++u)
        #pragma unroll
        for (int n = 0; n < 4; ++n)
            of[u][n] = (f32x4){0.f, 0.f, 0.f, 0.f};

    const float coef = 0.18033688011112042f;   // log2(e) / sqrt(64)
    int j0 = g * kpg;

    // bpermute source-lane byte indices (fixed per lane)
    const int s0   = ((quad & 1) << 5) + l16;
    const int idx0 = s0 << 2;
    const int idx1 = idx0 + 64;
    const bool hsel = quad >= 2;

    bf16x8 kfc[2][2];
    #pragma unroll
    for (int h = 0; h < 2; ++h)
        #pragma unroll
        for (int kc = 0; kc < 2; ++kc)
            kfc[h][kc] = *(const bf16x8*)(kb + (size_t)(j0 + h * 16 + l16) * 64 + kc * 32 + quad * 8);

    for (int it = 0; it < iters; ++it) {
        bf16x8 vf[4];
        #pragma unroll
        for (int n = 0; n < 4; ++n)
            vf[n] = *(const bf16x8*)(vT + (size_t)(n * 16 + l16) * NROW + j0 + quad * 8);
        const int jn = (it + 1 < iters) ? j0 + 32 : j0;
        bf16x8 kfn[2][2];
        #pragma unroll
        for (int h = 0; h < 2; ++h)
            #pragma unroll
            for (int kc = 0; kc < 2; ++kc)
                kfn[h][kc] = *(const bf16x8*)(kb + (size_t)(jn + h * 16 + l16) * 64 + kc * 32 + quad * 8);

        const f32x4 zero = (f32x4){0.f, 0.f, 0.f, 0.f};
        #pragma unroll
        for (int u = 0; u < 2; ++u) {
            // S^T tiles: C_h[key = h*16 + quad*4 + r][qrow = l16]
            f32x4 s0t = mfma16(kfc[0][0], qf[u][0], zero);
            s0t       = mfma16(kfc[0][1], qf[u][1], s0t);
            f32x4 s1t = mfma16(kfc[1][0], qf[u][0], zero);
            s1t       = mfma16(kfc[1][1], qf[u][1], s1t);
            float p[2][4];
            #pragma unroll
            for (int r = 0; r < 4; ++r) {
                p[0][r] = exp2f(s0t[r] * coef);
                p[1][r] = exp2f(s1t[r] * coef);
                lp[u] += p[0][r] + p[1][r];
            }
            int pk0lo = pack_bf2(p[0][0], p[0][1]);
            int pk0hi = pack_bf2(p[0][2], p[0][3]);
            int pk1lo = pack_bf2(p[1][0], p[1][1]);
            int pk1hi = pack_bf2(p[1][2], p[1][3]);
            // transpose to A-layout: A[m=l16][k=quad*8+j]
            int a0l = __builtin_amdgcn_ds_bpermute(idx0, pk0lo);
            int a0h = __builtin_amdgcn_ds_bpermute(idx0, pk0hi);
            int a1l = __builtin_amdgcn_ds_bpermute(idx0, pk1lo);
            int a1h = __builtin_amdgcn_ds_bpermute(idx0, pk1hi);
            int b0l = __builtin_amdgcn_ds_bpermute(idx1, pk0lo);
            int b0h = __builtin_amdgcn_ds_bpermute(idx1, pk0hi);
            int b1l = __builtin_amdgcn_ds_bpermute(idx1, pk1lo);
            int b1h = __builtin_amdgcn_ds_bpermute(idx1, pk1hi);
            union { int4 i; bf16x8 v; } cu;
            cu.i.x = hsel ? a1l : a0l;   // keys q*8+0,1
            cu.i.y = hsel ? a1h : a0h;   // keys q*8+2,3
            cu.i.z = hsel ? b1l : b0l;   // keys q*8+4,5
            cu.i.w = hsel ? b1h : b0h;   // keys q*8+6,7
            bf16x8 pf = cu.v;
            #pragma unroll
            for (int n = 0; n < 4; ++n)
                of[u][n] = mfma16(pf, vf[n], of[u][n]);
        }
        #pragma unroll
        for (int h = 0; h < 2; ++h)
            #pragma unroll
            for (int kc = 0; kc < 2; ++kc)
                kfc[h][kc] = kfn[h][kc];
        j0 += 32;
    }

    // l: reduce across quads (keys were split over quad positions)
    #pragma unroll
    for (int u = 0; u < 2; ++u) {
        float v = lp[u];
        v += __shfl_xor(v, 16, 64);
        v += __shfl_xor(v, 32, 64);
        lp[u] = v;
    }
    if (quad == 0) {
        #pragma unroll
        for (int u = 0; u < 2; ++u)
            atomicAdd(&lacc[r0 + u * 16 + l16], lp[u]);
    }
    #pragma unroll
    for (int u = 0; u < 2; ++u)
        #pragma unroll
        for (int n = 0; n < 4; ++n)
            #pragma unroll
            for (int r = 0; r < 4; ++r)
                atomicAdd(&Oacc[(r0 + u * 16 + quad * 4 + r) * 64 + n * 16 + l16],
                          of[u][n][r]);
}

// ---------------------------------------------------------------------------
// Kernel 3: normalize: q = Oacc/lacc, l2-normalize rows -> qnb (bf16).
__global__ __launch_bounds__(256) void norm_kernel(
    const float* __restrict__ Oacc, const float* __restrict__ lacc,
    __hip_bfloat16* __restrict__ qnb)
{
    const int r = blockIdx.x * 4 + (threadIdx.x >> 6);
    const int c = threadIdx.x & 63;
    float q = Oacc[(size_t)r * 64 + c] / lacc[r];
    float ss = q * q;
    ss += __shfl_xor(ss, 1, 64);
    ss += __shfl_xor(ss, 2, 64);
    ss += __shfl_xor(ss, 4, 64);
    ss += __shfl_xor(ss, 8, 64);
    ss += __shfl_xor(ss, 16, 64);
    ss += __shfl_xor(ss, 32, 64);
    qnb[(size_t)r * 64 + c] = __float2bfloat16(q * rsqrtf(fmaxf(ss, 1e-24f)));
}

// ---------------------------------------------------------------------------
// Kernel 4: sim = (1/128) * Vn(64x8192) @ Qn(64x8192)^T, split-K MFMA GEMM.
__global__ __launch_bounds__(64) void sim_kernel(
    const __hip_bfloat16* __restrict__ vnb,
    const __hip_bfloat16* __restrict__ qnb,
    float* __restrict__ out)
{
    const int lane = threadIdx.x;
    const int l16  = lane & 15;
    const int quad = lane >> 4;
    const int kblk = blockIdx.x * 64;

    f32x4 acc[4][4];
    #pragma unroll
    for (int mi = 0; mi < 4; ++mi)
        #pragma unroll
        for (int ni = 0; ni < 4; ++ni)
            acc[mi][ni] = (f32x4){0.f, 0.f, 0.f, 0.f};

    #pragma unroll
    for (int ks = 0; ks < 2; ++ks) {
        const int k0 = kblk + ks * 32 + quad * 8;
        bf16x8 af[4], bfv[4];
        #pragma unroll
        for (int mi = 0; mi < 4; ++mi)
            af[mi] = *(const bf16x8*)(vnb + (size_t)(mi * 16 + l16) * 8192 + k0);
        #pragma unroll
        for (int ni = 0; ni < 4; ++ni)
            bfv[ni] = *(const bf16x8*)(qnb + (size_t)(ni * 16 + l16) * 8192 + k0);
        #pragma unroll
        for (int mi = 0; mi < 4; ++mi)
            #pragma unroll
            for (int ni = 0; ni < 4; ++ni)
                acc[mi][ni] = mfma16(af[mi], bfv[ni], acc[mi][ni]);
    }

    #pragma unroll
    for (int mi = 0; mi < 4; ++mi)
        #pragma unroll
        for (int ni = 0; ni < 4; ++ni)
            #pragma unroll
            for (int r = 0; r < 4; ++r)
                atomicAdd(&out[(mi * 16 + quad * 4 + r) * 64 + ni * 16 + l16],
                          acc[mi][ni][r] * (1.f / 128.f));
}

// ---------------------------------------------------------------------------
extern "C" void kernel_launch(void* const* d_in, const int* in_sizes, int n_in,
                              void* d_out, int out_size, void* d_ws, size_t ws_size,
                              hipStream_t stream)
{
    const float* feat = (const float*)d_in[0];
    const float* Wq   = (const float*)d_in[1];
    const float* bq   = (const float*)d_in[2];
    const float* Wk   = (const float*)d_in[3];
    const float* bk   = (const float*)d_in[4];
    const float* Wv   = (const float*)d_in[5];
    const float* bv   = (const float*)d_in[6];
    float* out = (float*)d_out;

    const size_t MB = 1u << 20;
    char* ws = (char*)d_ws;
    __hip_bfloat16* qb  = (__hip_bfloat16*)(ws);             // 1 MB
    __hip_bfloat16* kb  = (__hip_bfloat16*)(ws + 1 * MB);    // 1 MB
    __hip_bfloat16* vT  = (__hip_bfloat16*)(ws + 2 * MB);    // 1 MB
    __hip_bfloat16* vnb = (__hip_bfloat16*)(ws + 3 * MB);    // 1 MB
    float* Oacc = (float*)(ws + 4 * MB);                     // 2 MB
    float* lacc = (float*)(ws + 6 * MB);                     // 32 KB
    __hip_bfloat16* qnb = (__hip_bfloat16*)(ws + 7 * MB);    // 1 MB

    (void)hipMemsetAsync(out, 0, 64 * 64 * sizeof(float), stream);
    (void)hipMemsetAsync(ws + 4 * MB, 0, 2 * MB + 32 * 1024, stream);  // Oacc+lacc
    proj_kernel<<<768, 256, 0, stream>>>(feat, Wq, bq, Wk, bk, Wv, bv, qb, kb, vT, vnb);
    attn_kernel<<<16 * 256, 64, 0, stream>>>(qb, kb, vT, Oacc, lacc);
    norm_kernel<<<2048, 256, 0, stream>>>(Oacc, lacc, qnb);
    sim_kernel<<<128, 64, 0, stream>>>(vnb, qnb, out);
}

// Round 7
// 158.748 us; speedup vs baseline: 1.0038x; 1.0038x over previous
//
#include <hip/hip_runtime.h>
#include <hip/hip_bf16.h>

#define NROW 8192   // B*A = 64*128
#define INC  128
#define OUTC 64

typedef __bf16 bf16x8 __attribute__((ext_vector_type(8)));
typedef __bf16 bf16x2 __attribute__((ext_vector_type(2)));
typedef float  f32x4  __attribute__((ext_vector_type(4)));

static __device__ __forceinline__ f32x4 mfma16(bf16x8 a, bf16x8 b, f32x4 c) {
    return __builtin_amdgcn_mfma_f32_16x16x32_bf16(a, b, c, 0, 0, 0);
}

static __device__ __forceinline__ bf16x8 cvt8(float4 lo, float4 hi) {
    bf16x8 r;
    r[0] = (__bf16)lo.x; r[1] = (__bf16)lo.y; r[2] = (__bf16)lo.z; r[3] = (__bf16)lo.w;
    r[4] = (__bf16)hi.x; r[5] = (__bf16)hi.y; r[6] = (__bf16)hi.z; r[7] = (__bf16)hi.w;
    return r;
}

static __device__ __forceinline__ int pack_bf2(float a, float b) {
    bf16x2 t; t[0] = (__bf16)a; t[1] = (__bf16)b;
    union { bf16x2 v; int i; } u; u.v = t;
    return u.i;
}

// ---------------------------------------------------------------------------
// Kernel 1: projection via MFMA. grid = 768 = mat(3) x b(64) x aq(4).
__global__ __launch_bounds__(256) void proj_kernel(
    const float* __restrict__ feat,
    const float* __restrict__ Wq, const float* __restrict__ bq,
    const float* __restrict__ Wk, const float* __restrict__ bk,
    const float* __restrict__ Wv, const float* __restrict__ bv,
    __hip_bfloat16* __restrict__ qb, __hip_bfloat16* __restrict__ kb,
    __hip_bfloat16* __restrict__ vT, __hip_bfloat16* __restrict__ vnb)
{
    __shared__ float slab[32 * 132];
    __shared__ float vbuf[32 * 66];
    __shared__ float invb[32];

    const int blk = blockIdx.x;
    const int mat = blk >> 8;
    const int b   = (blk >> 2) & 63;
    const int a0  = (blk & 3) * 32;
    const int r0  = b * 128 + a0;
    const float* fb = feat + (size_t)b * INC * 128;

    for (int i = threadIdx.x; i < 32 * 128; i += 256) {
        int c = i >> 5, a = i & 31;
        slab[a * 132 + c] = fb[c * 128 + a0 + a];
    }
    __syncthreads();

    const int w    = threadIdx.x >> 6;
    const int lane = threadIdx.x & 63;
    const int l16  = lane & 15;
    const int quad = lane >> 4;
    const int n0   = w * 16;

    const float* W    = (mat == 0) ? Wq : (mat == 1) ? Wk : Wv;
    const float* bias = (mat == 0) ? bq : (mat == 1) ? bk : bv;

    f32x4 acc[2] = {{0.f,0.f,0.f,0.f},{0.f,0.f,0.f,0.f}};
    #pragma unroll
    for (int kc = 0; kc < 4; ++kc) {
        const int k0 = kc * 32 + quad * 8;
        const float* wr = W + (n0 + l16) * INC + k0;
        bf16x8 bfr = cvt8(*(const float4*)wr, *(const float4*)(wr + 4));
        #pragma unroll
        for (int u = 0; u < 2; ++u) {
            const float* ar = slab + (u * 16 + l16) * 132 + k0;
            bf16x8 afr = cvt8(*(const float4*)ar, *(const float4*)(ar + 4));
            acc[u] = mfma16(afr, bfr, acc[u]);
        }
    }
    const float bl = bias[n0 + l16];

    if (mat < 2) {
        __hip_bfloat16* dst = mat ? kb : qb;
        #pragma unroll
        for (int u = 0; u < 2; ++u)
            #pragma unroll
            for (int r = 0; r < 4; ++r)
                dst[(r0 + u * 16 + quad * 4 + r) * OUTC + n0 + l16] =
                    __float2bfloat16(acc[u][r] + bl);
    } else {
        #pragma unroll
        for (int u = 0; u < 2; ++u)
            #pragma unroll
            for (int r = 0; r < 4; ++r)
                vbuf[(u * 16 + quad * 4 + r) * 66 + n0 + l16] = acc[u][r] + bl;
        __syncthreads();
        const int c  = threadIdx.x >> 2;
        const int rc = threadIdx.x & 3;
        bf16x8 pack;
        #pragma unroll
        for (int i = 0; i < 8; ++i)
            pack[i] = (__bf16)vbuf[(rc * 8 + i) * 66 + c];
        *(bf16x8*)(vT + (size_t)c * NROW + r0 + rc * 8) = pack;
        const int rl = threadIdx.x >> 3;
        const int jj = threadIdx.x & 7;
        float ss = 0.f;
        #pragma unroll
        for (int i = 0; i < 8; ++i) {
            float x = vbuf[rl * 66 + jj * 8 + i];
            ss += x * x;
        }
        ss += __shfl_xor(ss, 1, 64);
        ss += __shfl_xor(ss, 2, 64);
        ss += __shfl_xor(ss, 4, 64);
        if (jj == 0) invb[rl] = rsqrtf(fmaxf(ss, 1e-24f));
        __syncthreads();
        float inv = invb[rl];
        bf16x8 vp;
        #pragma unroll
        for (int i = 0; i < 8; ++i)
            vp[i] = (__bf16)(vbuf[rl * 66 + jj * 8 + i] * inv);
        *(bf16x8*)(vnb + (size_t)(r0 + rl) * 64 + jj * 8) = vp;
    }
}

// ---------------------------------------------------------------------------
// Kernel 2: attention, m97-style cooperative blocks.
// Block = 256 thr (4 waves), q-tile 128 rows (32/wave), key range 512 (G=16).
// Per 128-key chunk: stage K (16 KB) + V (16 KB) into XOR-swizzled LDS
// (register-staged, next chunk's loads issued before the compute barrier),
// then each wave runs 4x 32-key steps: S^T MFMA -> exp2 -> bpermute
// transpose (r6-verified) -> PV MFMA. Partials atomicAdd'ed to Oacc/lacc.
__global__ __launch_bounds__(256, 3) void attn_kernel(
    const __hip_bfloat16* __restrict__ qb,
    const __hip_bfloat16* __restrict__ kb,
    const __hip_bfloat16* __restrict__ vT,
    float* __restrict__ Oacc, float* __restrict__ lacc)
{
    __shared__ __align__(16) char klds[128 * 128];  // [key][chunk^(key&7)]  16 KB
    __shared__ __align__(16) char vlds[64 * 256];   // [t][chunk^(t&15)]     16 KB

    const int tid  = threadIdx.x;
    const int w    = tid >> 6;
    const int lane = tid & 63;
    const int l16  = lane & 15;
    const int quad = lane >> 4;
    const int qblk = blockIdx.x & 63;
    const int g    = blockIdx.x >> 6;
    const int r0   = qblk * 128 + w * 32;
    const int key0 = g * 512;

    // staging lane roles
    const int krow = tid >> 3;            // 0..31 (K rows per round)
    const int kcol = tid & 7;             // 16-B chunk within 128-B K row
    const int vrow = tid >> 4;            // 0..15 (V rows per round)
    const int vcol = tid & 15;            // 16-B chunk within 256-B V row
    const int kgsw = (kcol ^ (krow & 7)) * 16;
    const int vgsw = (vcol ^ (vrow & 15)) * 16;

    bf16x8 qf[2][2];
    #pragma unroll
    for (int u = 0; u < 2; ++u)
        #pragma unroll
        for (int kc = 0; kc < 2; ++kc)
            qf[u][kc] = *(const bf16x8*)(qb + (r0 + u * 16 + l16) * 64 + kc * 32 + quad * 8);

    f32x4 of[2][4];
    float lp[2] = {0.f, 0.f};
    #pragma unroll
    for (int u = 0; u < 2; ++u)
        #pragma unroll
        for (int n = 0; n < 4; ++n)
            of[u][n] = (f32x4){0.f, 0.f, 0.f, 0.f};

    const float coef = 0.18033688011112042f;   // log2(e) / sqrt(64)

    // bpermute source-lane byte indices (r6-verified pattern)
    const int idx0 = (((quad & 1) << 5) + l16) << 2;
    const int idx1 = idx0 + 64;
    const bool hsel = quad >= 2;

    const char* kbase = (const char*)kb;
    const char* vbase = (const char*)vT;

    float4 pK[4], pV[4];
    #pragma unroll
    for (int i = 0; i < 4; ++i) {
        pK[i] = *(const float4*)(kbase + (size_t)(key0 + i * 32 + krow) * 128 + kgsw);
        pV[i] = *(const float4*)(vbase + (size_t)(i * 16 + vrow) * (NROW * 2)
                                 + (size_t)key0 * 2 + vgsw);
    }

    for (int cc = 0; cc < 4; ++cc) {
        __syncthreads();   // previous chunk's LDS reads complete
        #pragma unroll
        for (int i = 0; i < 4; ++i) {
            *(float4*)(klds + (i * 32 + krow) * 128 + kcol * 16) = pK[i];
            *(float4*)(vlds + (i * 16 + vrow) * 256 + vcol * 16) = pV[i];
        }
        if (cc < 3) {
            const int nk0 = key0 + (cc + 1) * 128;
            #pragma unroll
            for (int i = 0; i < 4; ++i) {
                pK[i] = *(const float4*)(kbase + (size_t)(nk0 + i * 32 + krow) * 128 + kgsw);
                pV[i] = *(const float4*)(vbase + (size_t)(i * 16 + vrow) * (NROW * 2)
                                         + (size_t)nk0 * 2 + vgsw);
            }
        }
        __syncthreads();   // staging visible

        #pragma unroll
        for (int s = 0; s < 4; ++s) {
            bf16x8 kf[2][2];
            #pragma unroll
            for (int h = 0; h < 2; ++h)
                #pragma unroll
                for (int kc = 0; kc < 2; ++kc)
                    kf[h][kc] = *(const bf16x8*)(klds + (s * 32 + h * 16 + l16) * 128
                                                 + (((kc * 4 + quad) ^ (l16 & 7)) * 16));
            bf16x8 vf[4];
            #pragma unroll
            for (int n = 0; n < 4; ++n)
                vf[n] = *(const bf16x8*)(vlds + (n * 16 + l16) * 256
                                         + (((s * 4 + quad) ^ l16) * 16));

            const f32x4 zero = (f32x4){0.f, 0.f, 0.f, 0.f};
            #pragma unroll
            for (int u = 0; u < 2; ++u) {
                f32x4 s0t = mfma16(kf[0][0], qf[u][0], zero);
                s0t       = mfma16(kf[0][1], qf[u][1], s0t);
                f32x4 s1t = mfma16(kf[1][0], qf[u][0], zero);
                s1t       = mfma16(kf[1][1], qf[u][1], s1t);
                float p[2][4];
                #pragma unroll
                for (int r = 0; r < 4; ++r) {
                    p[0][r] = exp2f(s0t[r] * coef);
                    p[1][r] = exp2f(s1t[r] * coef);
                    lp[u] += p[0][r] + p[1][r];
                }
                int pk0lo = pack_bf2(p[0][0], p[0][1]);
                int pk0hi = pack_bf2(p[0][2], p[0][3]);
                int pk1lo = pack_bf2(p[1][0], p[1][1]);
                int pk1hi = pack_bf2(p[1][2], p[1][3]);
                int a0l = __builtin_amdgcn_ds_bpermute(idx0, pk0lo);
                int a0h = __builtin_amdgcn_ds_bpermute(idx0, pk0hi);
                int a1l = __builtin_amdgcn_ds_bpermute(idx0, pk1lo);
                int a1h = __builtin_amdgcn_ds_bpermute(idx0, pk1hi);
                int b0l = __builtin_amdgcn_ds_bpermute(idx1, pk0lo);
                int b0h = __builtin_amdgcn_ds_bpermute(idx1, pk0hi);
                int b1l = __builtin_amdgcn_ds_bpermute(idx1, pk1lo);
                int b1h = __builtin_amdgcn_ds_bpermute(idx1, pk1hi);
                union { int4 i; bf16x8 v; } cu;
                cu.i.x = hsel ? a1l : a0l;
                cu.i.y = hsel ? a1h : a0h;
                cu.i.z = hsel ? b1l : b0l;
                cu.i.w = hsel ? b1h : b0h;
                bf16x8 pf = cu.v;
                #pragma unroll
                for (int n = 0; n < 4; ++n)
                    of[u][n] = mfma16(pf, vf[n], of[u][n]);
            }
        }
    }

    #pragma unroll
    for (int u = 0; u < 2; ++u) {
        float v = lp[u];
        v += __shfl_xor(v, 16, 64);
        v += __shfl_xor(v, 32, 64);
        lp[u] = v;
    }
    if (quad == 0) {
        #pragma unroll
        for (int u = 0; u < 2; ++u)
            atomicAdd(&lacc[r0 + u * 16 + l16], lp[u]);
    }
    #pragma unroll
    for (int u = 0; u < 2; ++u)
        #pragma unroll
        for (int n = 0; n < 4; ++n)
            #pragma unroll
            for (int r = 0; r < 4; ++r)
                atomicAdd(&Oacc[(r0 + u * 16 + quad * 4 + r) * 64 + n * 16 + l16],
                          of[u][n][r]);
}

// ---------------------------------------------------------------------------
// Kernel 3: normalize: q = Oacc/lacc, l2-normalize rows -> qnb (bf16).
__global__ __launch_bounds__(256) void norm_kernel(
    const float* __restrict__ Oacc, const float* __restrict__ lacc,
    __hip_bfloat16* __restrict__ qnb)
{
    const int r = blockIdx.x * 4 + (threadIdx.x >> 6);
    const int c = threadIdx.x & 63;
    float q = Oacc[(size_t)r * 64 + c] / lacc[r];
    float ss = q * q;
    ss += __shfl_xor(ss, 1, 64);
    ss += __shfl_xor(ss, 2, 64);
    ss += __shfl_xor(ss, 4, 64);
    ss += __shfl_xor(ss, 8, 64);
    ss += __shfl_xor(ss, 16, 64);
    ss += __shfl_xor(ss, 32, 64);
    qnb[(size_t)r * 64 + c] = __float2bfloat16(q * rsqrtf(fmaxf(ss, 1e-24f)));
}

// ---------------------------------------------------------------------------
// Kernel 4: sim = (1/128) * Vn(64x8192) @ Qn(64x8192)^T, split-K MFMA GEMM.
// 32 blocks x 256 k each (4x less atomic contention than 128 x 64).
__global__ __launch_bounds__(64) void sim_kernel(
    const __hip_bfloat16* __restrict__ vnb,
    const __hip_bfloat16* __restrict__ qnb,
    float* __restrict__ out)
{
    const int lane = threadIdx.x;
    const int l16  = lane & 15;
    const int quad = lane >> 4;
    const int kblk = blockIdx.x * 256;

    f32x4 acc[4][4];
    #pragma unroll
    for (int mi = 0; mi < 4; ++mi)
        #pragma unroll
        for (int ni = 0; ni < 4; ++ni)
            acc[mi][ni] = (f32x4){0.f, 0.f, 0.f, 0.f};

    #pragma unroll
    for (int ks = 0; ks < 8; ++ks) {
        const int k0 = kblk + ks * 32 + quad * 8;
        bf16x8 af[4], bfv[4];
        #pragma unroll
        for (int mi = 0; mi < 4; ++mi)
            af[mi] = *(const bf16x8*)(vnb + (size_t)(mi * 16 + l16) * 8192 + k0);
        #pragma unroll
        for (int ni = 0; ni < 4; ++ni)
            bfv[ni] = *(const bf16x8*)(qnb + (size_t)(ni * 16 + l16) * 8192 + k0);
        #pragma unroll
        for (int mi = 0; mi < 4; ++mi)
            #pragma unroll
            for (int ni = 0; ni < 4; ++ni)
                acc[mi][ni] = mfma16(af[mi], bfv[ni], acc[mi][ni]);
    }

    #pragma unroll
    for (int mi = 0; mi < 4; ++mi)
        #pragma unroll
        for (int ni = 0; ni < 4; ++ni)
            #pragma unroll
            for (int r = 0; r < 4; ++r)
                atomicAdd(&out[(mi * 16 + quad * 4 + r) * 64 + ni * 16 + l16],
                          acc[mi][ni][r] * (1.f / 128.f));
}

// ---------------------------------------------------------------------------
extern "C" void kernel_launch(void* const* d_in, const int* in_sizes, int n_in,
                              void* d_out, int out_size, void* d_ws, size_t ws_size,
                              hipStream_t stream)
{
    const float* feat = (const float*)d_in[0];
    const float* Wq   = (const float*)d_in[1];
    const float* bq   = (const float*)d_in[2];
    const float* Wk   = (const float*)d_in[3];
    const float* bk   = (const float*)d_in[4];
    const float* Wv   = (const float*)d_in[5];
    const float* bv   = (const float*)d_in[6];
    float* out = (float*)d_out;

    const size_t MB = 1u << 20;
    char* ws = (char*)d_ws;
    __hip_bfloat16* qb  = (__hip_bfloat16*)(ws);             // 1 MB
    __hip_bfloat16* kb  = (__hip_bfloat16*)(ws + 1 * MB);    // 1 MB
    __hip_bfloat16* vT  = (__hip_bfloat16*)(ws + 2 * MB);    // 1 MB
    __hip_bfloat16* vnb = (__hip_bfloat16*)(ws + 3 * MB);    // 1 MB
    float* Oacc = (float*)(ws + 4 * MB);                     // 2 MB
    float* lacc = (float*)(ws + 6 * MB);                     // 32 KB
    __hip_bfloat16* qnb = (__hip_bfloat16*)(ws + 7 * MB);    // 1 MB

    (void)hipMemsetAsync(out, 0, 64 * 64 * sizeof(float), stream);
    (void)hipMemsetAsync(ws + 4 * MB, 0, 2 * MB + 32 * 1024, stream);  // Oacc+lacc
    proj_kernel<<<768, 256, 0, stream>>>(feat, Wq, bq, Wk, bk, Wv, bv, qb, kb, vT, vnb);
    attn_kernel<<<1024, 256, 0, stream>>>(qb, kb, vT, Oacc, lacc);
    norm_kernel<<<2048, 256, 0, stream>>>(Oacc, lacc, qnb);
    sim_kernel<<<32, 64, 0, stream>>>(vnb, qnb, out);
}

// Round 8
// 157.149 us; speedup vs baseline: 1.0140x; 1.0102x over previous
//
#include <hip/hip_runtime.h>
#include <hip/hip_bf16.h>

#define NROW 8192   // B*A = 64*128
#define INC  128
#define OUTC 64

typedef __bf16 bf16x8 __attribute__((ext_vector_type(8)));
typedef __bf16 bf16x2 __attribute__((ext_vector_type(2)));
typedef float  f32x4  __attribute__((ext_vector_type(4)));

static __device__ __forceinline__ f32x4 mfma16(bf16x8 a, bf16x8 b, f32x4 c) {
    return __builtin_amdgcn_mfma_f32_16x16x32_bf16(a, b, c, 0, 0, 0);
}

static __device__ __forceinline__ bf16x8 cvt8(float4 lo, float4 hi) {
    bf16x8 r;
    r[0] = (__bf16)lo.x; r[1] = (__bf16)lo.y; r[2] = (__bf16)lo.z; r[3] = (__bf16)lo.w;
    r[4] = (__bf16)hi.x; r[5] = (__bf16)hi.y; r[6] = (__bf16)hi.z; r[7] = (__bf16)hi.w;
    return r;
}

static __device__ __forceinline__ int pack_bf2(float a, float b) {
    bf16x2 t; t[0] = (__bf16)a; t[1] = (__bf16)b;
    union { bf16x2 v; int i; } u; u.v = t;
    return u.i;
}

// ---------------------------------------------------------------------------
// Kernel 1: projection via MFMA. grid = 768 = mat(3) x b(64) x aq(4).
__global__ __launch_bounds__(256) void proj_kernel(
    const float* __restrict__ feat,
    const float* __restrict__ Wq, const float* __restrict__ bq,
    const float* __restrict__ Wk, const float* __restrict__ bk,
    const float* __restrict__ Wv, const float* __restrict__ bv,
    __hip_bfloat16* __restrict__ qb, __hip_bfloat16* __restrict__ kb,
    __hip_bfloat16* __restrict__ vT, __hip_bfloat16* __restrict__ vnb)
{
    __shared__ float slab[32 * 132];
    __shared__ float vbuf[32 * 66];
    __shared__ float invb[32];

    const int blk = blockIdx.x;
    const int mat = blk >> 8;
    const int b   = (blk >> 2) & 63;
    const int a0  = (blk & 3) * 32;
    const int r0  = b * 128 + a0;
    const float* fb = feat + (size_t)b * INC * 128;

    for (int i = threadIdx.x; i < 32 * 128; i += 256) {
        int c = i >> 5, a = i & 31;
        slab[a * 132 + c] = fb[c * 128 + a0 + a];
    }
    __syncthreads();

    const int w    = threadIdx.x >> 6;
    const int lane = threadIdx.x & 63;
    const int l16  = lane & 15;
    const int quad = lane >> 4;
    const int n0   = w * 16;

    const float* W    = (mat == 0) ? Wq : (mat == 1) ? Wk : Wv;
    const float* bias = (mat == 0) ? bq : (mat == 1) ? bk : bv;

    f32x4 acc[2] = {{0.f,0.f,0.f,0.f},{0.f,0.f,0.f,0.f}};
    #pragma unroll
    for (int kc = 0; kc < 4; ++kc) {
        const int k0 = kc * 32 + quad * 8;
        const float* wr = W + (n0 + l16) * INC + k0;
        bf16x8 bfr = cvt8(*(const float4*)wr, *(const float4*)(wr + 4));
        #pragma unroll
        for (int u = 0; u < 2; ++u) {
            const float* ar = slab + (u * 16 + l16) * 132 + k0;
            bf16x8 afr = cvt8(*(const float4*)ar, *(const float4*)(ar + 4));
            acc[u] = mfma16(afr, bfr, acc[u]);
        }
    }
    const float bl = bias[n0 + l16];

    if (mat < 2) {
        __hip_bfloat16* dst = mat ? kb : qb;
        #pragma unroll
        for (int u = 0; u < 2; ++u)
            #pragma unroll
            for (int r = 0; r < 4; ++r)
                dst[(r0 + u * 16 + quad * 4 + r) * OUTC + n0 + l16] =
                    __float2bfloat16(acc[u][r] + bl);
    } else {
        #pragma unroll
        for (int u = 0; u < 2; ++u)
            #pragma unroll
            for (int r = 0; r < 4; ++r)
                vbuf[(u * 16 + quad * 4 + r) * 66 + n0 + l16] = acc[u][r] + bl;
        __syncthreads();
        const int c  = threadIdx.x >> 2;
        const int rc = threadIdx.x & 3;
        bf16x8 pack;
        #pragma unroll
        for (int i = 0; i < 8; ++i)
            pack[i] = (__bf16)vbuf[(rc * 8 + i) * 66 + c];
        *(bf16x8*)(vT + (size_t)c * NROW + r0 + rc * 8) = pack;
        const int rl = threadIdx.x >> 3;
        const int jj = threadIdx.x & 7;
        float ss = 0.f;
        #pragma unroll
        for (int i = 0; i < 8; ++i) {
            float x = vbuf[rl * 66 + jj * 8 + i];
            ss += x * x;
        }
        ss += __shfl_xor(ss, 1, 64);
        ss += __shfl_xor(ss, 2, 64);
        ss += __shfl_xor(ss, 4, 64);
        if (jj == 0) invb[rl] = rsqrtf(fmaxf(ss, 1e-24f));
        __syncthreads();
        float inv = invb[rl];
        bf16x8 vp;
        #pragma unroll
        for (int i = 0; i < 8; ++i)
            vp[i] = (__bf16)(vbuf[rl * 66 + jj * 8 + i] * inv);
        *(bf16x8*)(vnb + (size_t)(r0 + rl) * 64 + jj * 8) = vp;
    }
}

// ---------------------------------------------------------------------------
// Kernel 2: attention, cooperative 4-wave blocks, STREAMING partial output.
// Block = 256 thr, q-tile 128 rows (32/wave), key range 512 (G=16).
// Per 128-key chunk: stage K (16 KB) + V (16 KB) into XOR-swizzled LDS
// (register-staged, next chunk's loads issued before the compute barrier),
// then each wave runs 4x 32-key steps: S^T MFMA -> exp2 -> bpermute
// transpose -> PV MFMA. Epilogue: plain coalesced fp32 writes to
// Opart[block]/lpart[block] (NO atomics — r7 showed 8.4M device atomics
// cost 139 MB of RMW HBM traffic = the whole kernel's runtime).
__global__ __launch_bounds__(256, 3) void attn_kernel(
    const __hip_bfloat16* __restrict__ qb,
    const __hip_bfloat16* __restrict__ kb,
    const __hip_bfloat16* __restrict__ vT,
    float* __restrict__ Opart, float* __restrict__ lpart)
{
    __shared__ __align__(16) char klds[128 * 128];  // [key][chunk^(key&7)]  16 KB
    __shared__ __align__(16) char vlds[64 * 256];   // [t][chunk^(t&15)]     16 KB

    const int tid  = threadIdx.x;
    const int w    = tid >> 6;
    const int lane = tid & 63;
    const int l16  = lane & 15;
    const int quad = lane >> 4;
    const int qblk = blockIdx.x & 63;
    const int g    = blockIdx.x >> 6;
    const int r0   = qblk * 128 + w * 32;
    const int key0 = g * 512;

    const int krow = tid >> 3;
    const int kcol = tid & 7;
    const int vrow = tid >> 4;
    const int vcol = tid & 15;
    const int kgsw = (kcol ^ (krow & 7)) * 16;
    const int vgsw = (vcol ^ (vrow & 15)) * 16;

    bf16x8 qf[2][2];
    #pragma unroll
    for (int u = 0; u < 2; ++u)
        #pragma unroll
        for (int kc = 0; kc < 2; ++kc)
            qf[u][kc] = *(const bf16x8*)(qb + (r0 + u * 16 + l16) * 64 + kc * 32 + quad * 8);

    f32x4 of[2][4];
    float lp[2] = {0.f, 0.f};
    #pragma unroll
    for (int u = 0; u < 2; ++u)
        #pragma unroll
        for (int n = 0; n < 4; ++n)
            of[u][n] = (f32x4){0.f, 0.f, 0.f, 0.f};

    const float coef = 0.18033688011112042f;   // log2(e) / sqrt(64)

    const int idx0 = (((quad & 1) << 5) + l16) << 2;
    const int idx1 = idx0 + 64;
    const bool hsel = quad >= 2;

    const char* kbase = (const char*)kb;
    const char* vbase = (const char*)vT;

    float4 pK[4], pV[4];
    #pragma unroll
    for (int i = 0; i < 4; ++i) {
        pK[i] = *(const float4*)(kbase + (size_t)(key0 + i * 32 + krow) * 128 + kgsw);
        pV[i] = *(const float4*)(vbase + (size_t)(i * 16 + vrow) * (NROW * 2)
                                 + (size_t)key0 * 2 + vgsw);
    }

    for (int cc = 0; cc < 4; ++cc) {
        __syncthreads();
        #pragma unroll
        for (int i = 0; i < 4; ++i) {
            *(float4*)(klds + (i * 32 + krow) * 128 + kcol * 16) = pK[i];
            *(float4*)(vlds + (i * 16 + vrow) * 256 + vcol * 16) = pV[i];
        }
        if (cc < 3) {
            const int nk0 = key0 + (cc + 1) * 128;
            #pragma unroll
            for (int i = 0; i < 4; ++i) {
                pK[i] = *(const float4*)(kbase + (size_t)(nk0 + i * 32 + krow) * 128 + kgsw);
                pV[i] = *(const float4*)(vbase + (size_t)(i * 16 + vrow) * (NROW * 2)
                                         + (size_t)nk0 * 2 + vgsw);
            }
        }
        __syncthreads();

        #pragma unroll
        for (int s = 0; s < 4; ++s) {
            bf16x8 kf[2][2];
            #pragma unroll
            for (int h = 0; h < 2; ++h)
                #pragma unroll
                for (int kc = 0; kc < 2; ++kc)
                    kf[h][kc] = *(const bf16x8*)(klds + (s * 32 + h * 16 + l16) * 128
                                                 + (((kc * 4 + quad) ^ (l16 & 7)) * 16));
            bf16x8 vf[4];
            #pragma unroll
            for (int n = 0; n < 4; ++n)
                vf[n] = *(const bf16x8*)(vlds + (n * 16 + l16) * 256
                                         + (((s * 4 + quad) ^ l16) * 16));

            const f32x4 zero = (f32x4){0.f, 0.f, 0.f, 0.f};
            #pragma unroll
            for (int u = 0; u < 2; ++u) {
                f32x4 s0t = mfma16(kf[0][0], qf[u][0], zero);
                s0t       = mfma16(kf[0][1], qf[u][1], s0t);
                f32x4 s1t = mfma16(kf[1][0], qf[u][0], zero);
                s1t       = mfma16(kf[1][1], qf[u][1], s1t);
                float p[2][4];
                #pragma unroll
                for (int r = 0; r < 4; ++r) {
                    p[0][r] = exp2f(s0t[r] * coef);
                    p[1][r] = exp2f(s1t[r] * coef);
                    lp[u] += p[0][r] + p[1][r];
                }
                int pk0lo = pack_bf2(p[0][0], p[0][1]);
                int pk0hi = pack_bf2(p[0][2], p[0][3]);
                int pk1lo = pack_bf2(p[1][0], p[1][1]);
                int pk1hi = pack_bf2(p[1][2], p[1][3]);
                int a0l = __builtin_amdgcn_ds_bpermute(idx0, pk0lo);
                int a0h = __builtin_amdgcn_ds_bpermute(idx0, pk0hi);
                int a1l = __builtin_amdgcn_ds_bpermute(idx0, pk1lo);
                int a1h = __builtin_amdgcn_ds_bpermute(idx0, pk1hi);
                int b0l = __builtin_amdgcn_ds_bpermute(idx1, pk0lo);
                int b0h = __builtin_amdgcn_ds_bpermute(idx1, pk0hi);
                int b1l = __builtin_amdgcn_ds_bpermute(idx1, pk1lo);
                int b1h = __builtin_amdgcn_ds_bpermute(idx1, pk1hi);
                union { int4 i; bf16x8 v; } cu;
                cu.i.x = hsel ? a1l : a0l;
                cu.i.y = hsel ? a1h : a0h;
                cu.i.z = hsel ? b1l : b0l;
                cu.i.w = hsel ? b1h : b0h;
                bf16x8 pf = cu.v;
                #pragma unroll
                for (int n = 0; n < 4; ++n)
                    of[u][n] = mfma16(pf, vf[n], of[u][n]);
            }
        }
    }

    // l: reduce across quads, then streaming write
    #pragma unroll
    for (int u = 0; u < 2; ++u) {
        float v = lp[u];
        v += __shfl_xor(v, 16, 64);
        v += __shfl_xor(v, 32, 64);
        lp[u] = v;
    }
    if (quad == 0) {
        lpart[blockIdx.x * 128 + w * 32 + l16]      = lp[0];
        lpart[blockIdx.x * 128 + w * 32 + 16 + l16] = lp[1];
    }
    float* Ob = Opart + (size_t)blockIdx.x * (128 * 64) + (w * 32) * 64;
    #pragma unroll
    for (int u = 0; u < 2; ++u)
        #pragma unroll
        for (int n = 0; n < 4; ++n)
            #pragma unroll
            for (int r = 0; r < 4; ++r)
                Ob[(u * 16 + quad * 4 + r) * 64 + n * 16 + l16] = of[u][n][r];
}

// ---------------------------------------------------------------------------
// Kernel 3: combine split-K partials, divide by l, l2-normalize -> qnb (bf16).
// task = g*64 + qblk; Opart[task] is a 128x64 slab.
__global__ __launch_bounds__(256) void combine_kernel(
    const float* __restrict__ Opart, const float* __restrict__ lpart,
    __hip_bfloat16* __restrict__ qnb)
{
    const int r    = blockIdx.x * 4 + (threadIdx.x >> 6);
    const int c    = threadIdx.x & 63;
    const int qblk = r >> 7;
    const int lr   = r & 127;
    float acc = 0.f, lsum = 0.f;
    #pragma unroll
    for (int g = 0; g < 16; ++g) {
        int task = g * 64 + qblk;
        acc  += Opart[(size_t)task * 8192 + lr * 64 + c];
        lsum += lpart[task * 128 + lr];
    }
    float q = acc / lsum;
    float ss = q * q;
    ss += __shfl_xor(ss, 1, 64);
    ss += __shfl_xor(ss, 2, 64);
    ss += __shfl_xor(ss, 4, 64);
    ss += __shfl_xor(ss, 8, 64);
    ss += __shfl_xor(ss, 16, 64);
    ss += __shfl_xor(ss, 32, 64);
    qnb[(size_t)r * 64 + c] = __float2bfloat16(q * rsqrtf(fmaxf(ss, 1e-24f)));
}

// ---------------------------------------------------------------------------
// Kernel 4: sim = (1/128) * Vn(64x8192) @ Qn(64x8192)^T, split-K MFMA GEMM.
__global__ __launch_bounds__(64) void sim_kernel(
    const __hip_bfloat16* __restrict__ vnb,
    const __hip_bfloat16* __restrict__ qnb,
    float* __restrict__ out)
{
    const int lane = threadIdx.x;
    const int l16  = lane & 15;
    const int quad = lane >> 4;
    const int kblk = blockIdx.x * 256;

    f32x4 acc[4][4];
    #pragma unroll
    for (int mi = 0; mi < 4; ++mi)
        #pragma unroll
        for (int ni = 0; ni < 4; ++ni)
            acc[mi][ni] = (f32x4){0.f, 0.f, 0.f, 0.f};

    #pragma unroll
    for (int ks = 0; ks < 8; ++ks) {
        const int k0 = kblk + ks * 32 + quad * 8;
        bf16x8 af[4], bfv[4];
        #pragma unroll
        for (int mi = 0; mi < 4; ++mi)
            af[mi] = *(const bf16x8*)(vnb + (size_t)(mi * 16 + l16) * 8192 + k0);
        #pragma unroll
        for (int ni = 0; ni < 4; ++ni)
            bfv[ni] = *(const bf16x8*)(qnb + (size_t)(ni * 16 + l16) * 8192 + k0);
        #pragma unroll
        for (int mi = 0; mi < 4; ++mi)
            #pragma unroll
            for (int ni = 0; ni < 4; ++ni)
                acc[mi][ni] = mfma16(af[mi], bfv[ni], acc[mi][ni]);
    }

    #pragma unroll
    for (int mi = 0; mi < 4; ++mi)
        #pragma unroll
        for (int ni = 0; ni < 4; ++ni)
            #pragma unroll
            for (int r = 0; r < 4; ++r)
                atomicAdd(&out[(mi * 16 + quad * 4 + r) * 64 + ni * 16 + l16],
                          acc[mi][ni][r] * (1.f / 128.f));
}

// ---------------------------------------------------------------------------
extern "C" void kernel_launch(void* const* d_in, const int* in_sizes, int n_in,
                              void* d_out, int out_size, void* d_ws, size_t ws_size,
                              hipStream_t stream)
{
    const float* feat = (const float*)d_in[0];
    const float* Wq   = (const float*)d_in[1];
    const float* bq   = (const float*)d_in[2];
    const float* Wk   = (const float*)d_in[3];
    const float* bk   = (const float*)d_in[4];
    const float* Wv   = (const float*)d_in[5];
    const float* bv   = (const float*)d_in[6];
    float* out = (float*)d_out;

    const size_t MB = 1u << 20;
    char* ws = (char*)d_ws;
    __hip_bfloat16* qb  = (__hip_bfloat16*)(ws);              // 1 MB
    __hip_bfloat16* kb  = (__hip_bfloat16*)(ws + 1 * MB);     // 1 MB
    __hip_bfloat16* vT  = (__hip_bfloat16*)(ws + 2 * MB);     // 1 MB
    __hip_bfloat16* vnb = (__hip_bfloat16*)(ws + 3 * MB);     // 1 MB
    float* Opart = (float*)(ws + 4 * MB);                     // 32 MB (1024 x 32 KB)
    float* lpart = (float*)(ws + 36 * MB);                    // 512 KB
    __hip_bfloat16* qnb = (__hip_bfloat16*)(ws + 37 * MB);    // 1 MB

    (void)hipMemsetAsync(out, 0, 64 * 64 * sizeof(float), stream);
    proj_kernel<<<768, 256, 0, stream>>>(feat, Wq, bq, Wk, bk, Wv, bv, qb, kb, vT, vnb);
    attn_kernel<<<1024, 256, 0, stream>>>(qb, kb, vT, Opart, lpart);
    combine_kernel<<<2048, 256, 0, stream>>>(Opart, lpart, qnb);
    sim_kernel<<<32, 64, 0, stream>>>(vnb, qnb, out);
}